// Round 2
// baseline (615.382 us; speedup 1.0000x reference)
//
#include <hip/hip_runtime.h>

// segments: (8, 1, 512, 512) f32, values 0..63; downsample ::2 -> (8, 256, 256)
// R=7, K_SIDE=15, 225 offsets, zero-padded OOB neighbors (pad=0.0 can MATCH seg==0!)
// out: (8, 225, 256, 256) f32 = 471.9 MB  -> write-BW floor ~75 us
//
// R4: single kernel, NO workspace dependency (R3's fast path was gated on
// ws_size >= 2.35 MB; identical dur_us to R2 says the slow fallback ran).
// Plane-major decomposition kept: block = (plane, 64-row chunk, batch) writes
// a CONTIGUOUS 64 KB stream. Reads go straight to the full-res input
// (8 MB, L2/L3-resident; each element used once per plane, so staging buys
// nothing). Grid ordered x-fastest so the 225 plane-blocks sharing one
// (chunk,b) input window dispatch together -> window stays hot in every L2.
// Own pixels: two aligned dwordx4 + even-lane extract (stride-2 in regs).
// Neighbor pixels: 4 clamped scalar loads + select(0.0f) for zero-pad.

#define RAD 7
#define KS 15
#define HW 256
#define IN_W 512
#define PLANE (HW * HW)          // 65536

typedef float vf4 __attribute__((ext_vector_type(4)));

__global__ __launch_bounds__(256) void adj_direct(const float* __restrict__ in,
                                                  float* __restrict__ out) {
    const int p  = blockIdx.x;            // 0..224
    const int y0 = blockIdx.y * 64;       // 0,64,128,192
    const int b  = blockIdx.z;            // 0..7
    const int dy = p / KS;                // 0..14
    const int dx = p - dy * KS;           // 0..14

    const int tid  = threadIdx.x;
    const int wv   = tid >> 6;            // wave 0..3
    const int lane = tid & 63;
    const int x    = lane * 4;            // this lane's 4 output columns

    const float* inb = in + (size_t)b * (IN_W * IN_W);
    float* ob = out + ((size_t)(b * (KS * KS) + p)) * PLANE
                    + (size_t)y0 * HW + x;

    const int nx0 = x + dx - RAD;         // first neighbor column (downsampled)

    // waves interleave rows y0+wv, +4, ... so the block's 64 KB store stream
    // advances linearly.
    for (int yi = wv; yi < 64; yi += 4) {
        const int y  = y0 + yi;
        const int ny = y + dy - RAD;
        const bool yok = (unsigned)ny < (unsigned)HW;

        // own segment ids: full-res row 2y, cols 2x..2x+7 -> two aligned vf4,
        // take even elements (stride-2 downsample in registers)
        const float* orow = inb + (size_t)(2 * y) * IN_W + 2 * x;
        const vf4 o0 = *(const vf4*)(orow);
        const vf4 o1 = *(const vf4*)(orow + 4);
        const float s0 = o0.x, s1 = o0.z, s2 = o1.x, s3 = o1.z;

        // neighbor row (clamped to row 0 when OOB; value replaced by 0.0f)
        const float* nrow = inb + (size_t)(2 * (yok ? ny : 0)) * IN_W;
        float n[4];
        #pragma unroll
        for (int k = 0; k < 4; ++k) {
            const int c  = nx0 + k;                        // downsampled col
            const bool ok = yok && ((unsigned)c < (unsigned)HW);
            const float v = nrow[ok ? 2 * c : 0];          // clamped, safe load
            n[k] = ok ? v : 0.0f;                          // zero-pad semantics
        }

        vf4 r;
        r.x = (s0 == n[0]) ? 1.0f : 0.0f;
        r.y = (s1 == n[1]) ? 1.0f : 0.0f;
        r.z = (s2 == n[2]) ? 1.0f : 0.0f;
        r.w = (s3 == n[3]) ? 1.0f : 0.0f;
        __builtin_nontemporal_store(r, (vf4*)(ob + (size_t)yi * HW));
    }
}

extern "C" void kernel_launch(void* const* d_in, const int* in_sizes, int n_in,
                              void* d_out, int out_size, void* d_ws, size_t ws_size,
                              hipStream_t stream) {
    const float* segments = (const float*)d_in[0];
    float* out = (float*)d_out;
    // x fastest: 225 plane-blocks sharing one (chunk,b) input window dispatch
    // back-to-back -> L2 window locality on every XCD.
    dim3 grid(KS * KS, 4, 8);
    dim3 block(256);
    adj_direct<<<grid, block, 0, stream>>>(segments, out);
}

// Round 3
// 611.148 us; speedup vs baseline: 1.0069x; 1.0069x over previous
//
#include <hip/hip_runtime.h>

// segments: (8, 1, 512, 512) f32, values 0..63; downsample ::2 -> (8, 256, 256)
// R=7, K_SIDE=15, 225 offsets, zero-padded OOB neighbors (pad=0.0 can MATCH seg==0)
// out: (8, 225, 256, 256) f32 = 471.9 MB  -> write floor ~75 us @ 6.3 TB/s
//
// R5: dur_us includes the harness ~300us re-poison fill (our kernel never shows
// in top-5: it is <297us). Ours was ~160us (R2/R3-dense) vs 315us (R4 strided
// order) -> aggregate cross-block store stream order is what matters.
// fillBuffer proves 6.3 TB/s on this buffer; we got 2.95. This round removes
// the two remaining differences vs fillBuffer:
//   1. grid-stride OUTPUT-LINEAR mapping: each loop iteration the whole
//      resident grid writes one dense 8 MB window, sliding monotonically --
//      exactly fillBuffer's pattern. No dependence on block dispatch order.
//   2. plain stores (NO nontemporal hint) -- fill uses plain stores; NT
//      evict-first may defeat L2 write combining.
// Reads stay direct (input 8 MB, L2/L3-resident; R2's LDS staging vs R3/R4
// direct reads showed no difference). Wave-uniform (b,p,y) decode from the
// linear float4 index: shifts + two constant divisions.

#define RAD 7
#define KS 15
#define HW 256
#define IN_W 512
#define PLANE (HW * HW)                        // 65536
#define TOTAL_V4 (8u * KS * KS * (PLANE / 4))  // 29,491,200 float4 outputs

typedef float vf4 __attribute__((ext_vector_type(4)));

__global__ __launch_bounds__(256) void adj_linear(const float* __restrict__ in,
                                                  float* __restrict__ out) {
    const unsigned gsize = gridDim.x * 256u;
    for (unsigned t = blockIdx.x * 256u + threadIdx.x; t < TOTAL_V4; t += gsize) {
        // decode linear float4 index -> (b, p, y, x); (b,p,y) wave-uniform
        const unsigned plane_id = t >> 14;          // 0..1799 = b*225 + p
        const unsigned within   = t & 16383u;
        const unsigned y        = within >> 6;      // 0..255
        const unsigned x        = (within & 63u) * 4u;
        const unsigned b        = plane_id / 225u;  // const-div -> magic mul
        const unsigned p        = plane_id - b * 225u;
        const unsigned dy       = p / 15u;
        const unsigned dx       = p - dy * 15u;

        const float* inb = in + (size_t)b * (IN_W * IN_W);

        // own segment ids: full-res row 2y, cols 2x..2x+7, stride-2 extract
        const float* orow = inb + (size_t)(2u * y) * IN_W + 2u * x;
        const vf4 o0 = *(const vf4*)(orow);
        const vf4 o1 = *(const vf4*)(orow + 4);
        const float s0 = o0.x, s1 = o0.z, s2 = o1.x, s3 = o1.z;

        // neighbor row (clamped when OOB; value replaced by 0.0f = pad)
        const int ny   = (int)y + (int)dy - RAD;
        const bool yok = (unsigned)ny < (unsigned)HW;
        const float* nrow = inb + (size_t)(2 * (yok ? ny : 0)) * IN_W;
        const int nx0 = (int)x + (int)dx - RAD;
        float n[4];
        #pragma unroll
        for (int k = 0; k < 4; ++k) {
            const int c   = nx0 + k;
            const bool ok = yok && ((unsigned)c < (unsigned)HW);
            const float v = nrow[ok ? 2 * c : 0];   // clamped, safe load
            n[k] = ok ? v : 0.0f;                   // zero-pad semantics
        }

        vf4 r;
        r.x = (s0 == n[0]) ? 1.0f : 0.0f;
        r.y = (s1 == n[1]) ? 1.0f : 0.0f;
        r.z = (s2 == n[2]) ? 1.0f : 0.0f;
        r.w = (s3 == n[3]) ? 1.0f : 0.0f;
        *(vf4*)(out + ((size_t)t << 2)) = r;        // plain store, no NT
    }
}

extern "C" void kernel_launch(void* const* d_in, const int* in_sizes, int n_in,
                              void* d_out, int out_size, void* d_ws, size_t ws_size,
                              hipStream_t stream) {
    const float* segments = (const float*)d_in[0];
    float* out = (float*)d_out;
    // 2048 blocks = ~8/CU, all resident; resident set is a contiguous blockIdx
    // range -> each grid-stride step writes one dense 8 MB window.
    adj_linear<<<dim3(2048), dim3(256), 0, stream>>>(segments, out);
}

// Round 4
// 576.120 us; speedup vs baseline: 1.0681x; 1.0608x over previous
//
#include <hip/hip_runtime.h>

// segments: (8, 1, 512, 512) f32, values 0..63; downsample ::2 -> (8, 256, 256)
// R=7, K_SIDE=15, 225 offsets, zero-padded OOB (pad=0.0 CAN match seg==0)
// out: (8, 225, 256, 256) f32 = 471.9 MB -> write floor ~75 us @ 6.3 TB/s
//
// R6: fix BOTH taxes at once.
//  - Write tax: block = (chunk,p,b) owns a CONTIGUOUS 32 KB output region
//    (32 rows of one plane) and walks it monotonically -> DRAM row locality
//    guaranteed per-block, immune to block drift (R5's failure mode: grid-
//    stride blocks desync, aggregate becomes 2048 scattered 1KB cursors).
//  - Read tax: R4/R5 read via stride-32B gathers (~12 KB of cache lines per
//    1 KB stored, ~150 us of L1-line traffic). Now stage the 46-row halo
//    window into LDS with aligned full-res dwordx4 (lane-consecutive, 1 KB
//    dense per instr, 100% line use), extract even lanes in registers.
//    Even/odd pair trick: LDS col pair (2p-8, 2p-7) <-> full-res cols
//    4p-16..4p-13, and pairs never straddle the 0/256 boundary.
//  - Plain stores (R4 vs R5 showed NT is a non-factor).
// 50 KB static LDS -> 3 blocks/CU; store-bound, occupancy is ample.

#define RAD 7
#define KS 15
#define HW 256
#define IN_W 512
#define PLANE (HW * HW)        // 65536
#define CH 32                  // output rows per block
#define SROWS (CH + 2 * RAD)   // 46
#define SPITCH 272             // 8 left pad + 256 + 8 right pad
#define NPAIR (SPITCH / 2)     // 136

typedef float vf4 __attribute__((ext_vector_type(4)));

__global__ __launch_bounds__(256) void adj_chunk(const float* __restrict__ in,
                                                 float* __restrict__ out) {
    __shared__ float smem[SROWS][SPITCH];   // 50,048 B

    const int chunk = blockIdx.x;          // 0..7 (32-row chunk)
    const int p     = blockIdx.y;          // 0..224
    const int b     = blockIdx.z;          // 0..7
    const int y0    = chunk * CH;
    const int dy    = p / KS;
    const int dx    = p - dy * KS;
    const int tid   = threadIdx.x;

    const float* inb = in + (size_t)b * (IN_W * IN_W);

    // Stage downsampled rows [y0-7, y0+38] x cols [-8, 263], zero-padded.
    // Task i -> (r, pr): ds row y0-7+r, ds col pair (2pr-8, 2pr-7).
    for (int i = tid; i < SROWS * NPAIR; i += 256) {
        const int r  = i / NPAIR;          // magic-mul const div
        const int pr = i - r * NPAIR;
        const int g  = y0 - RAD + r;       // ds row
        const int c0 = 2 * pr - 8;         // first ds col of the pair
        float v0 = 0.0f, v1 = 0.0f;
        if ((unsigned)g < (unsigned)HW && (unsigned)c0 < (unsigned)HW) {
            // full-res: row 2g, cols 4pr-16 .. 4pr-13 (16B-aligned)
            const vf4 q = *(const vf4*)(inb + (size_t)(2 * g) * IN_W + 2 * c0);
            v0 = q.x;                      // even cols = downsample
            v1 = q.z;
        }
        smem[r][2 * pr]     = v0;
        smem[r][2 * pr + 1] = v1;
    }
    __syncthreads();

    const int wv   = tid >> 6;
    const int lane = tid & 63;
    const int x    = lane * 4;             // this lane's 4 output columns

    float* ob = out + ((size_t)(b * (KS * KS) + p)) * PLANE
                    + (size_t)y0 * HW + x;

    // 4 waves interleave rows yi = wv, wv+4, ...: block's 32 KB region is
    // written front-to-back.
    for (int yi = wv; yi < CH; yi += 4) {
        // own ids: ds row y0+yi -> LDS row yi+7, col x -> LDS col 8+x (16B-aligned)
        const vf4 own = *(const vf4*)&smem[yi + RAD][8 + x];
        // neighbor: ds row y0+yi+dy-7 -> LDS row yi+dy; col x+k+dx-7 -> LDS col x+dx+1+k
        const float* np = &smem[yi + dy][x + dx + 1];
        vf4 r;
        r.x = (own.x == np[0]) ? 1.0f : 0.0f;
        r.y = (own.y == np[1]) ? 1.0f : 0.0f;
        r.z = (own.z == np[2]) ? 1.0f : 0.0f;
        r.w = (own.w == np[3]) ? 1.0f : 0.0f;
        *(vf4*)(ob + (size_t)yi * HW) = r;  // plain store
    }
}

extern "C" void kernel_launch(void* const* d_in, const int* in_sizes, int n_in,
                              void* d_out, int out_size, void* d_ws, size_t ws_size,
                              hipStream_t stream) {
    const float* segments = (const float*)d_in[0];
    float* out = (float*)d_out;
    dim3 grid(8, KS * KS, 8);   // (chunk, p, b)
    dim3 block(256);
    adj_chunk<<<grid, block, 0, stream>>>(segments, out);
}

// Round 5
// 459.194 us; speedup vs baseline: 1.3401x; 1.2546x over previous
//
#include <hip/hip_runtime.h>

// segments: (8, 1, 512, 512) f32, values 0..63; downsample ::2 -> (8, 256, 256)
// R=7, K_SIDE=15, 225 offsets, zero-padded OOB (pad=0.0 CAN match seg==0)
// out: (8, 225, 256, 256) f32 = 471.9 MB -> write floor ~75 us @ 6.3 TB/s
//
// R7: combine the three things no prior round had together:
//  - READ REUSE (R2's win): stage a 22-row halo band ONCE per block (24 KB
//    LDS, ~45 KB global), then write that band for 113 planes (0.9 MB out).
//    Staging cost ~2% of stores (R6's 3:1 ratio was the regression cause).
//  - LONG WRITE RUNS (R3-fallback's win): 8 waves = 8 adjacent rows -> each
//    plane-iteration the block emits one dense 8 KB run (8x R2's 1 KB runs
//    that capped DRAM row amortization at 2.95 TB/s).
//  - LDS-ONLY INNER LOOP (neither had): per 1 KB stored: 2 aligned
//    ds_read_b128 + ~16 VALU + 1 store. No global gathers (R3/R4/R5's
//    VMEM-issue tax), no barriers in the hot loop, own-IDs hoisted to regs.
// Neighbor col x+dx-7 is misaligned; read two aligned vf4 at
// x + ((dx+1)&~3) and select by wave-uniform s=(dx+1)&3 (4-case switch,
// uniform branch -- no dynamic reg indexing).
// Grid (32 bands, 8 b, 2 plane-halves) = 512 blocks = 2/CU, 16 waves/CU.

#define RAD 7
#define KS 15
#define HW 256
#define IN_W 512
#define PLANE (HW * HW)         // 65536
#define CH 8                    // rows per band = waves per block
#define SROWS (CH + 2 * RAD)    // 22
#define SPITCH 272              // 8 left pad + 256 + 8 right pad
#define NPAIR (SPITCH / 2)      // 136
#define NTASK (SROWS * NPAIR)   // 2992

typedef float vf4 __attribute__((ext_vector_type(4)));

__global__ __launch_bounds__(512) void adj_rowband(const float* __restrict__ in,
                                                   float* __restrict__ out) {
    __shared__ float smem[SROWS][SPITCH];   // 23,936 B

    const int band = blockIdx.x;            // 0..31
    const int b    = blockIdx.y;            // 0..7
    const int pg   = blockIdx.z;            // 0..1
    const int y0   = band * CH;
    const int p_begin = pg ? 113 : 0;
    const int p_end   = pg ? 225 : 113;

    const int tid = threadIdx.x;
    const float* inb = in + (size_t)b * (IN_W * IN_W);

    // Stage ds rows [y0-7, y0+14] x ds cols [-8, 263], zero-padded.
    // Task i -> (r, pr): LDS col pair (2pr, 2pr+1) = ds cols (2pr-8, 2pr-7),
    // from one aligned full-res vf4 (even elements = downsample).
    for (int i = tid; i < NTASK; i += 512) {
        const int r  = i / NPAIR;
        const int pr = i - r * NPAIR;
        const int g  = y0 - RAD + r;        // ds row
        const int c0 = 2 * pr - 8;          // first ds col of pair
        float v0 = 0.0f, v1 = 0.0f;
        if ((unsigned)g < (unsigned)HW && (unsigned)c0 < (unsigned)HW) {
            const vf4 q = *(const vf4*)(inb + (size_t)(2 * g) * IN_W + 2 * c0);
            v0 = q.x;
            v1 = q.z;
        }
        smem[r][2 * pr]     = v0;
        smem[r][2 * pr + 1] = v1;
    }
    __syncthreads();

    const int wv   = tid >> 6;              // 0..7: this wave's row in band
    const int lane = tid & 63;
    const int x    = lane * 4;              // 4 output columns

    // own segment ids: fixed per wave, hoisted out of the plane loop
    const vf4 own = *(const vf4*)&smem[wv + RAD][8 + x];
    const float s0 = own.x, s1 = own.y, s2 = own.z, s3 = own.w;

    float* op = out + ((size_t)(b * (KS * KS) + p_begin)) * PLANE
                    + (size_t)(y0 + wv) * HW + x;

    for (int p = p_begin; p < p_end; ++p, op += PLANE) {
        const int dy = p / KS;              // uniform (SALU magic-mul)
        const int dx = p - dy * KS;
        // neighbor (y0+wv+dy-7, x+k+dx-7) -> LDS row wv+dy, col x+dx+1+k
        const float* nrow = &smem[wv + dy][0];
        const int d4 = (dx + 1) & ~3;       // aligned start (x mult of 4)
        const vf4 w0 = *(const vf4*)(nrow + x + d4);
        const vf4 w1 = *(const vf4*)(nrow + x + d4 + 4);
        vf4 r;
        switch ((dx + 1) & 3) {             // wave-uniform select
        case 0:
            r.x = (s0 == w0.x) ? 1.f : 0.f; r.y = (s1 == w0.y) ? 1.f : 0.f;
            r.z = (s2 == w0.z) ? 1.f : 0.f; r.w = (s3 == w0.w) ? 1.f : 0.f;
            break;
        case 1:
            r.x = (s0 == w0.y) ? 1.f : 0.f; r.y = (s1 == w0.z) ? 1.f : 0.f;
            r.z = (s2 == w0.w) ? 1.f : 0.f; r.w = (s3 == w1.x) ? 1.f : 0.f;
            break;
        case 2:
            r.x = (s0 == w0.z) ? 1.f : 0.f; r.y = (s1 == w0.w) ? 1.f : 0.f;
            r.z = (s2 == w1.x) ? 1.f : 0.f; r.w = (s3 == w1.y) ? 1.f : 0.f;
            break;
        default:
            r.x = (s0 == w0.w) ? 1.f : 0.f; r.y = (s1 == w1.x) ? 1.f : 0.f;
            r.z = (s2 == w1.y) ? 1.f : 0.f; r.w = (s3 == w1.z) ? 1.f : 0.f;
            break;
        }
        __builtin_nontemporal_store(r, (vf4*)op);
    }
}

extern "C" void kernel_launch(void* const* d_in, const int* in_sizes, int n_in,
                              void* d_out, int out_size, void* d_ws, size_t ws_size,
                              hipStream_t stream) {
    const float* segments = (const float*)d_in[0];
    float* out = (float*)d_out;
    dim3 grid(32, 8, 2);    // (band, batch, plane-half)
    dim3 block(512);
    adj_rowband<<<grid, block, 0, stream>>>(segments, out);
}